// Round 1
// baseline (438.736 us; speedup 1.0000x reference)
//
#include <hip/hip_runtime.h>

#define HWD 56
#define NWIN 7
#define P2 49
#define CIN 128
#define COUT 384
#define NB 8
#define SCALE 0.08838834764831843f

// ---------------- QKV projection: qkv = x_win @ W + b ----------------
// grid (49, 8, 2), block 256. Output layout: [n][p][pix][384] (q 0..127, k 128..255, v 256..383)
__global__ __launch_bounds__(256) void qkv_proj_kernel(
    const float* __restrict__ xin, const float* __restrict__ yin,
    const float* __restrict__ Wx, const float* __restrict__ Bx,
    const float* __restrict__ Wy, const float* __restrict__ By,
    float* __restrict__ qkvx, float* __restrict__ qkvy)
{
  const int p = blockIdx.x, n = blockIdx.y, br = blockIdx.z;
  const float* X  = br ? yin : xin;
  const float* W  = br ? Wy  : Wx;
  const float* Bv = br ? By  : Bx;
  float* out = br ? qkvy : qkvx;

  __shared__ float xs[64][132];   // [token][cin], pad 132 to spread banks
  __shared__ float wt[32][128];   // [k-chunk][cout-tile]

  const int t = threadIdx.x;
  const int wr = p / NWIN, wc = p % NWIN;

  // stage x window tile: 64 tokens x 128 ch (coalesced)
#pragma unroll
  for (int i = 0; i < 32; ++i) {
    int e = t + i * 256;
    int tok = e >> 7, k = e & 127;
    int a = wr * 8 + (tok >> 3);
    int b = wc * 8 + (tok & 7);
    xs[tok][k] = X[(((size_t)n * HWD + a) * HWD + b) * CIN + k];
  }

  const int tc = t & 15, tr = t >> 4;  // 16x16 thread grid: 8 ch x 4 tokens microtile

  for (int ch0 = 0; ch0 < COUT; ch0 += 128) {
    float acc[4][8];
#pragma unroll
    for (int i = 0; i < 4; ++i)
#pragma unroll
      for (int j = 0; j < 8; ++j) acc[i][j] = 0.f;

    for (int k0 = 0; k0 < 128; k0 += 32) {
      __syncthreads();  // protects wt from previous chunk's readers
#pragma unroll
      for (int i = 0; i < 16; ++i) {
        int e = t + i * 256;
        int kk = e >> 7, cc = e & 127;
        wt[kk][cc] = W[(size_t)(k0 + kk) * COUT + ch0 + cc];
      }
      __syncthreads();
#pragma unroll
      for (int kk = 0; kk < 32; ++kk) {
        float4 w0 = *(const float4*)&wt[kk][tc * 8];
        float4 w1 = *(const float4*)&wt[kk][tc * 8 + 4];
#pragma unroll
        for (int i = 0; i < 4; ++i) {
          float xv = xs[tr * 4 + i][k0 + kk];
          acc[i][0] = fmaf(xv, w0.x, acc[i][0]);
          acc[i][1] = fmaf(xv, w0.y, acc[i][1]);
          acc[i][2] = fmaf(xv, w0.z, acc[i][2]);
          acc[i][3] = fmaf(xv, w0.w, acc[i][3]);
          acc[i][4] = fmaf(xv, w1.x, acc[i][4]);
          acc[i][5] = fmaf(xv, w1.y, acc[i][5]);
          acc[i][6] = fmaf(xv, w1.z, acc[i][6]);
          acc[i][7] = fmaf(xv, w1.w, acc[i][7]);
        }
      }
    }
#pragma unroll
    for (int i = 0; i < 4; ++i) {
      int tok = tr * 4 + i;
      size_t base = (((size_t)(n * P2 + p)) * 64 + tok) * COUT + ch0 + tc * 8;
#pragma unroll
      for (int j = 0; j < 8; ++j) out[base + j] = acc[i][j] + Bv[ch0 + tc * 8 + j];
    }
  }
}

// ---------------- window means (q_win, k_win) ----------------
// grid (49, 8, 2), block 256 (one thread per channel 0..255)
__global__ __launch_bounds__(256) void win_mean_kernel(
    const float* __restrict__ qkvx, const float* __restrict__ qkvy,
    float* __restrict__ qwx, float* __restrict__ kwx,
    float* __restrict__ qwy, float* __restrict__ kwy)
{
  const int p = blockIdx.x, n = blockIdx.y, br = blockIdx.z;
  const float* qkv = br ? qkvy : qkvx;
  float* qw = br ? qwy : qwx;
  float* kw = br ? kwy : kwx;
  const int c = threadIdx.x;
  float s = 0.f;
  size_t base = ((size_t)(n * P2 + p)) * 64 * COUT + c;
  for (int pix = 0; pix < 64; ++pix) s += qkv[base + (size_t)pix * COUT];
  s *= (1.f / 64.f);
  if (c < 128) qw[(n * P2 + p) * 128 + c] = s;
  else         kw[(n * P2 + p) * 128 + (c - 128)] = s;
}

// ---------------- routing: top-4 window indices ----------------
// grid (2, 8), block 64; thread r handles query-window r (<49)
__global__ __launch_bounds__(64) void route_kernel(
    const float* __restrict__ qwx, const float* __restrict__ kwx,
    const float* __restrict__ qwy, const float* __restrict__ kwy,
    int* __restrict__ idxx, int* __restrict__ idxy)
{
  const int br = blockIdx.x, n = blockIdx.y;
  const float* qw = br ? qwy : qwx;
  const float* kw = br ? kwy : kwx;
  int* idx = br ? idxy : idxx;

  __shared__ float qs[P2][128];
  __shared__ float ks[P2][128];
  const int t = threadIdx.x;
  for (int e = t; e < P2 * 128; e += 64) {
    qs[e >> 7][e & 127] = qw[(size_t)n * P2 * 128 + e];
    ks[e >> 7][e & 127] = kw[(size_t)n * P2 * 128 + e];
  }
  __syncthreads();
  if (t < P2) {
    float logit[P2];
    for (int j = 0; j < P2; ++j) {
      float d = 0.f;
      for (int c = 0; c < 128; ++c) d += qs[t][c] * ks[j][c];
      logit[j] = d;  // scale>0 is monotone: ordering identical
    }
    int ch[4];
    for (int s = 0; s < 4; ++s) {
      float best = -1e30f; int bi = 0;
      for (int j = 0; j < P2; ++j) {
        bool taken = false;
        for (int u = 0; u < s; ++u) taken = taken || (ch[u] == j);
        if (!taken && logit[j] > best) { best = logit[j]; bi = j; }
      }
      ch[s] = bi;
      idx[((size_t)n * P2 + t) * 4 + s] = bi;
    }
  }
}

// ---------------- fused gather + attention (cross branches) ----------------
// grid (49, 8, 16): z = head*2 + dir
//   dir 0: q=x, k=x(idxx), v=y(idxy) -> writes out_y (second half of d_out)
//   dir 1: q=y, k=y(idxy), v=x(idxx) -> writes out_x (first half)
__global__ __launch_bounds__(256) void attn_kernel(
    const float* __restrict__ qkvx, const float* __restrict__ qkvy,
    const int* __restrict__ idxx, const int* __restrict__ idxy,
    float* __restrict__ dout)
{
  const int p = blockIdx.x, n = blockIdx.y, z = blockIdx.z;
  const int h = z >> 1, dir = z & 1;
  const float* qkvQ = dir ? qkvy : qkvx;   // q and k branch
  const float* qkvV = dir ? qkvx : qkvy;   // v branch (cross)
  const int* idxK = dir ? idxy : idxx;
  const int* idxV = dir ? idxx : idxy;
  const size_t OUTHALF = (size_t)NB * HWD * HWD * CIN;
  float* outp = dout + (dir ? 0 : OUTHALF);

  __shared__ float kb[256][20];  // pad 20: key-stride spreads banks, keeps 16B align
  __shared__ float vb[256][20];
  __shared__ float qb[64][16];
  __shared__ int   widx[8];      // [0..3] k-windows, [4..7] v-windows

  const int t = threadIdx.x;
  if (t < 4)       widx[t] = idxK[((size_t)n * P2 + p) * 4 + t];
  else if (t < 8)  widx[t] = idxV[((size_t)n * P2 + p) * 4 + (t - 4)];
  __syncthreads();

  // gather K (ch 128 + h*16 + d) and V (ch 256 + h*16 + d); key = kk*64 + pix
#pragma unroll
  for (int i = 0; i < 4; ++i) {
    int fi = i * 256 + t;
    int key = fi >> 2, d4 = fi & 3;
    int kk = key >> 6, pix = key & 63;
    {
      int wK = widx[kk];
      float4 v = *(const float4*)&qkvQ[(((size_t)(n * P2 + wK)) * 64 + pix) * COUT + 128 + h * 16 + d4 * 4];
      *(float4*)&kb[key][d4 * 4] = v;
    }
    {
      int wV = widx[4 + kk];
      float4 v = *(const float4*)&qkvV[(((size_t)(n * P2 + wV)) * 64 + pix) * COUT + 256 + h * 16 + d4 * 4];
      *(float4*)&vb[key][d4 * 4] = v;
    }
  }
  {
    int qr = t >> 2, d4 = t & 3;
    float4 v = *(const float4*)&qkvQ[(((size_t)(n * P2 + p)) * 64 + qr) * COUT + h * 16 + d4 * 4];
    *(float4*)&qb[qr][d4 * 4] = v;
  }
  __syncthreads();

  // thread owns rows {rg, rg+32}, keys {kg + 8i}; 8 threads cooperate per row
  const int rg = t >> 3;      // 0..31
  const int kg = t & 7;       // 0..7
  const int r0 = rg, r1 = rg + 32;

  float q0[16], q1[16];
#pragma unroll
  for (int d4 = 0; d4 < 4; ++d4) {
    float4 a = *(const float4*)&qb[r0][d4 * 4];
    q0[d4 * 4 + 0] = a.x; q0[d4 * 4 + 1] = a.y; q0[d4 * 4 + 2] = a.z; q0[d4 * 4 + 3] = a.w;
    float4 b = *(const float4*)&qb[r1][d4 * 4];
    q1[d4 * 4 + 0] = b.x; q1[d4 * 4 + 1] = b.y; q1[d4 * 4 + 2] = b.z; q1[d4 * 4 + 3] = b.w;
  }

  float sc0[32], sc1[32];
#pragma unroll
  for (int i = 0; i < 32; ++i) {
    int key = kg + 8 * i;
    float kv[16];
#pragma unroll
    for (int d4 = 0; d4 < 4; ++d4) {
      float4 a = *(const float4*)&kb[key][d4 * 4];
      kv[d4 * 4 + 0] = a.x; kv[d4 * 4 + 1] = a.y; kv[d4 * 4 + 2] = a.z; kv[d4 * 4 + 3] = a.w;
    }
    float d0 = 0.f, d1 = 0.f;
#pragma unroll
    for (int d = 0; d < 16; ++d) { d0 = fmaf(q0[d], kv[d], d0); d1 = fmaf(q1[d], kv[d], d1); }
    sc0[i] = d0 * SCALE;
    sc1[i] = d1 * SCALE;
  }

  // row-wise softmax across 8 cooperating lanes
  float m0 = -1e30f, m1 = -1e30f;
#pragma unroll
  for (int i = 0; i < 32; ++i) { m0 = fmaxf(m0, sc0[i]); m1 = fmaxf(m1, sc1[i]); }
#pragma unroll
  for (int msk = 1; msk < 8; msk <<= 1) {
    m0 = fmaxf(m0, __shfl_xor(m0, msk));
    m1 = fmaxf(m1, __shfl_xor(m1, msk));
  }
  float s0 = 0.f, s1 = 0.f;
#pragma unroll
  for (int i = 0; i < 32; ++i) {
    sc0[i] = __expf(sc0[i] - m0); s0 += sc0[i];
    sc1[i] = __expf(sc1[i] - m1); s1 += sc1[i];
  }
#pragma unroll
  for (int msk = 1; msk < 8; msk <<= 1) {
    s0 += __shfl_xor(s0, msk);
    s1 += __shfl_xor(s1, msk);
  }
  const float inv0 = 1.f / s0, inv1 = 1.f / s1;

  // PV
  float acc0[16], acc1[16];
#pragma unroll
  for (int d = 0; d < 16; ++d) { acc0[d] = 0.f; acc1[d] = 0.f; }
#pragma unroll
  for (int i = 0; i < 32; ++i) {
    int key = kg + 8 * i;
    float vv[16];
#pragma unroll
    for (int d4 = 0; d4 < 4; ++d4) {
      float4 a = *(const float4*)&vb[key][d4 * 4];
      vv[d4 * 4 + 0] = a.x; vv[d4 * 4 + 1] = a.y; vv[d4 * 4 + 2] = a.z; vv[d4 * 4 + 3] = a.w;
    }
    float p0 = sc0[i], p1 = sc1[i];
#pragma unroll
    for (int d = 0; d < 16; ++d) { acc0[d] = fmaf(p0, vv[d], acc0[d]); acc1[d] = fmaf(p1, vv[d], acc1[d]); }
  }
#pragma unroll
  for (int msk = 1; msk < 8; msk <<= 1) {
#pragma unroll
    for (int d = 0; d < 16; ++d) {
      acc0[d] += __shfl_xor(acc0[d], msk);
      acc1[d] += __shfl_xor(acc1[d], msk);
    }
  }

  if (kg == 0) {
    const int wr = p / NWIN, wc = p % NWIN;
    {
      int a = wr * 8 + (r0 >> 3), b = wc * 8 + (r0 & 7);
      size_t base = (((size_t)n * HWD + a) * HWD + b) * CIN + h * 16;
#pragma unroll
      for (int d4 = 0; d4 < 4; ++d4)
        *(float4*)&outp[base + d4 * 4] = make_float4(acc0[d4*4+0]*inv0, acc0[d4*4+1]*inv0, acc0[d4*4+2]*inv0, acc0[d4*4+3]*inv0);
    }
    {
      int a = wr * 8 + (r1 >> 3), b = wc * 8 + (r1 & 7);
      size_t base = (((size_t)n * HWD + a) * HWD + b) * CIN + h * 16;
#pragma unroll
      for (int d4 = 0; d4 < 4; ++d4)
        *(float4*)&outp[base + d4 * 4] = make_float4(acc1[d4*4+0]*inv1, acc1[d4*4+1]*inv1, acc1[d4*4+2]*inv1, acc1[d4*4+3]*inv1);
    }
  }
}

// ---------------- depthwise 3x3 LEPE + add into d_out ----------------
// grid (56, 56, 16): z = n*2 + br; block 128 (channel)
__global__ __launch_bounds__(128) void lepe_kernel(
    const float* __restrict__ qkvx, const float* __restrict__ qkvy,
    const float* __restrict__ wlx, const float* __restrict__ blx,
    const float* __restrict__ wly, const float* __restrict__ bly,
    float* __restrict__ dout)
{
  const int a = blockIdx.x, b = blockIdx.y;
  const int n = blockIdx.z >> 1, br = blockIdx.z & 1;
  const float* qkv = br ? qkvy : qkvx;
  const float* wl = br ? wly : wlx;
  const float* bl = br ? bly : blx;
  const size_t OUTHALF = (size_t)NB * HWD * HWD * CIN;
  float* outp = dout + (br ? OUTHALF : 0);
  const int c = threadIdx.x;

  float s = bl[c];
#pragma unroll
  for (int di = 0; di < 3; ++di) {
    int aa = a + di - 1;
    if ((unsigned)aa < (unsigned)HWD) {
#pragma unroll
      for (int dj = 0; dj < 3; ++dj) {
        int bb = b + dj - 1;
        if ((unsigned)bb < (unsigned)HWD) {
          int pp = (aa >> 3) * NWIN + (bb >> 3);
          int pix = ((aa & 7) << 3) + (bb & 7);
          float v = qkv[(((size_t)(n * P2 + pp)) * 64 + pix) * COUT + 256 + c];
          s = fmaf(v, wl[c * 9 + di * 3 + dj], s);
        }
      }
    }
  }
  size_t o = (((size_t)n * HWD + a) * HWD + b) * CIN + c;
  outp[o] += s;
}

extern "C" void kernel_launch(void* const* d_in, const int* in_sizes, int n_in,
                              void* d_out, int out_size, void* d_ws, size_t ws_size,
                              hipStream_t stream) {
  const float* x        = (const float*)d_in[0];
  const float* y        = (const float*)d_in[1];
  const float* w_qkv_x  = (const float*)d_in[2];
  const float* b_qkv_x  = (const float*)d_in[3];
  const float* w_qkv_y  = (const float*)d_in[4];
  const float* b_qkv_y  = (const float*)d_in[5];
  const float* w_lepe_x = (const float*)d_in[6];
  const float* b_lepe_x = (const float*)d_in[7];
  const float* w_lepe_y = (const float*)d_in[8];
  const float* b_lepe_y = (const float*)d_in[9];
  float* out = (float*)d_out;
  float* ws  = (float*)d_ws;

  const size_t qkv_sz = (size_t)NB * P2 * 64 * COUT;   // 9,633,792 floats
  const size_t win_sz = (size_t)NB * P2 * 128;         // 50,176 floats
  float* qkvx = ws;
  float* qkvy = qkvx + qkv_sz;
  float* qwx  = qkvy + qkv_sz;
  float* kwx  = qwx + win_sz;
  float* qwy  = kwx + win_sz;
  float* kwy  = qwy + win_sz;
  int*   idxx = (int*)(kwy + win_sz);
  int*   idxy = idxx + NB * P2 * 4;

  qkv_proj_kernel<<<dim3(P2, NB, 2), 256, 0, stream>>>(x, y, w_qkv_x, b_qkv_x, w_qkv_y, b_qkv_y, qkvx, qkvy);
  win_mean_kernel<<<dim3(P2, NB, 2), 256, 0, stream>>>(qkvx, qkvy, qwx, kwx, qwy, kwy);
  route_kernel<<<dim3(2, NB), 64, 0, stream>>>(qwx, kwx, qwy, kwy, idxx, idxy);
  attn_kernel<<<dim3(P2, NB, 16), 256, 0, stream>>>(qkvx, qkvy, idxx, idxy, out);
  lepe_kernel<<<dim3(HWD, HWD, 2 * NB), 128, 0, stream>>>(qkvx, qkvy, w_lepe_x, b_lepe_x, w_lepe_y, b_lepe_y, out);
}

// Round 2
// 422.524 us; speedup vs baseline: 1.0384x; 1.0384x over previous
//
#include <hip/hip_runtime.h>

#define HWD 56
#define NWIN 7
#define P2 49
#define CIN 128
#define COUT 384
#define NB 8
#define SCALE 0.08838834764831843f

typedef __attribute__((ext_vector_type(8))) short bf16x8;
typedef __attribute__((ext_vector_type(4))) float f32x4;
typedef __attribute__((ext_vector_type(8))) unsigned short u16x8;

__device__ inline unsigned short f2bf(float f) {
  unsigned int u = __float_as_uint(f);
  unsigned int r = (u + 0x7fffu + ((u >> 16) & 1u)) >> 16;
  return (unsigned short)r;
}

// ---------------- QKV projection + fused window means ----------------
// grid (49, 8, 2), block 384 (8 tok-groups x 48 ch-groups, 8x8 microtile)
__global__ __launch_bounds__(384) void qkv_proj_kernel(
    const float* __restrict__ xin, const float* __restrict__ yin,
    const float* __restrict__ Wx, const float* __restrict__ Bx,
    const float* __restrict__ Wy, const float* __restrict__ By,
    float* __restrict__ qkvx, float* __restrict__ qkvy,
    float* __restrict__ qwx, float* __restrict__ kwx,
    float* __restrict__ qwy, float* __restrict__ kwy)
{
  const int p = blockIdx.x, n = blockIdx.y, br = blockIdx.z;
  const float* X  = br ? yin : xin;
  const float* W  = br ? Wy  : Wx;
  const float* Bv = br ? By  : Bx;
  float* out = br ? qkvy : qkvx;
  float* qw  = br ? qwy : qwx;
  float* kw  = br ? kwy : kwx;

  __shared__ float xs_t[128][68];  // [ch][tok], pad 68 keeps float4 align, rows shift 4 banks
  __shared__ float wt[8][384];     // k-chunk of 8 x full 384 cout
  __shared__ float sm[8][256];     // mean partials [tok-group][ch]

  const int t = threadIdx.x;
  const int wr = p / NWIN, wc = p % NWIN;

  // stage x transposed (coalesced global read, scalar LDS write)
  for (int e = t; e < 64 * 128; e += 384) {
    int tok = e >> 7, ch = e & 127;
    int a = wr * 8 + (tok >> 3);
    int b = wc * 8 + (tok & 7);
    xs_t[ch][tok] = X[(((size_t)n * HWD + a) * HWD + b) * CIN + ch];
  }

  const int cg = t % 48, tg = t / 48;   // ch-group (8 ch), tok-group (8 tok)

  float acc[8][8];
#pragma unroll
  for (int i = 0; i < 8; ++i)
#pragma unroll
    for (int j = 0; j < 8; ++j) acc[i][j] = 0.f;

  for (int kc = 0; kc < 16; ++kc) {
    __syncthreads();
#pragma unroll
    for (int i = 0; i < 8; ++i) wt[i][t] = W[(size_t)(kc * 8 + i) * COUT + t];
    __syncthreads();
#pragma unroll
    for (int kk = 0; kk < 8; ++kk) {
      int k = kc * 8 + kk;
      float4 xa = *(const float4*)&xs_t[k][tg * 8];
      float4 xb = *(const float4*)&xs_t[k][tg * 8 + 4];
      float4 wa = *(const float4*)&wt[kk][cg * 8];
      float4 wb = *(const float4*)&wt[kk][cg * 8 + 4];
      float xv[8] = {xa.x, xa.y, xa.z, xa.w, xb.x, xb.y, xb.z, xb.w};
      float wv[8] = {wa.x, wa.y, wa.z, wa.w, wb.x, wb.y, wb.z, wb.w};
#pragma unroll
      for (int i = 0; i < 8; ++i)
#pragma unroll
        for (int j = 0; j < 8; ++j) acc[i][j] = fmaf(xv[i], wv[j], acc[i][j]);
    }
  }

  // bias + store
  float bv[8];
#pragma unroll
  for (int j = 0; j < 8; ++j) bv[j] = Bv[cg * 8 + j];
#pragma unroll
  for (int i = 0; i < 8; ++i) {
    int tok = tg * 8 + i;
    size_t base = ((size_t)(n * P2 + p) * 64 + tok) * COUT + cg * 8;
    float4 o0 = make_float4(acc[i][0] + bv[0], acc[i][1] + bv[1], acc[i][2] + bv[2], acc[i][3] + bv[3]);
    float4 o1 = make_float4(acc[i][4] + bv[4], acc[i][5] + bv[5], acc[i][6] + bv[6], acc[i][7] + bv[7]);
    *(float4*)&out[base] = o0;
    *(float4*)&out[base + 4] = o1;
  }

  // fused means over q (ch 0..127) and k (ch 128..255)
  if (cg < 32) {
#pragma unroll
    for (int j = 0; j < 8; ++j) {
      float s = 0.f;
#pragma unroll
      for (int i = 0; i < 8; ++i) s += acc[i][j];
      sm[tg][cg * 8 + j] = s;
    }
  }
  __syncthreads();
  if (t < 256) {
    float s = 0.f;
#pragma unroll
    for (int g = 0; g < 8; ++g) s += sm[g][t];
    s = s * (1.f / 64.f) + Bv[t];
    if (t < 128) qw[(n * P2 + p) * 128 + t] = s;
    else         kw[(n * P2 + p) * 128 + (t - 128)] = s;
  }
}

// ---------------- routing: top-4 window indices ----------------
// grid (2, 8), block 256
__global__ __launch_bounds__(256) void route_kernel(
    const float* __restrict__ qwx, const float* __restrict__ kwx,
    const float* __restrict__ qwy, const float* __restrict__ kwy,
    int* __restrict__ idxx, int* __restrict__ idxy)
{
  const int br = blockIdx.x, n = blockIdx.y;
  const float* qw = br ? qwy : qwx;
  const float* kw = br ? kwy : kwx;
  int* idx = br ? idxy : idxx;

  __shared__ float qs[P2][128];
  __shared__ float ks[P2][128];
  __shared__ float ls[P2][52];
  const int t = threadIdx.x;
  for (int e = t; e < P2 * 128; e += 256) {
    qs[e >> 7][e & 127] = qw[(size_t)n * P2 * 128 + e];
    ks[e >> 7][e & 127] = kw[(size_t)n * P2 * 128 + e];
  }
  __syncthreads();
  for (int pair = t; pair < P2 * P2; pair += 256) {
    int r = pair / P2, j = pair % P2;
    float d = 0.f;
#pragma unroll
    for (int c4 = 0; c4 < 32; ++c4) {
      float4 a = *(const float4*)&qs[r][c4 * 4];
      float4 b = *(const float4*)&ks[j][c4 * 4];
      d = fmaf(a.x, b.x, d); d = fmaf(a.y, b.y, d);
      d = fmaf(a.z, b.z, d); d = fmaf(a.w, b.w, d);
    }
    ls[r][j] = d;  // positive scale is monotone: ordering identical
  }
  __syncthreads();
  if (t < P2) {
    int ch[4];
    for (int s = 0; s < 4; ++s) {
      float best = -1e30f; int bi = 0;
      for (int j = 0; j < P2; ++j) {
        bool taken = false;
        for (int u = 0; u < s; ++u) taken = taken || (ch[u] == j);
        if (!taken && ls[t][j] > best) { best = ls[t][j]; bi = j; }
      }
      ch[s] = bi;
      idx[((size_t)n * P2 + t) * 4 + s] = bi;
    }
  }
}

// ---------------- fused gather + MFMA flash attention (cross branches) ----------------
// grid (49, 8, 16): z = head*2 + dir; block 256 = 4 waves, wave w owns q-rows [16w,16w+16)
//   dir 0: q=x, k=x(idxx), v=y(idxy) -> writes out_y (second half of d_out)
//   dir 1: q=y, k=y(idxy), v=x(idxx) -> writes out_x (first half)
__global__ __launch_bounds__(256) void attn_kernel(
    const float* __restrict__ qkvx, const float* __restrict__ qkvy,
    const int* __restrict__ idxx, const int* __restrict__ idxy,
    float* __restrict__ dout)
{
  const int p = blockIdx.x, n = blockIdx.y, z = blockIdx.z;
  const int h = z >> 1, dir = z & 1;
  const float* qkvQ = dir ? qkvy : qkvx;
  const float* qkvV = dir ? qkvx : qkvy;
  const int* idxK = dir ? idxy : idxx;
  const int* idxV = dir ? idxx : idxy;
  const size_t OUTHALF = (size_t)NB * HWD * HWD * CIN;
  float* outp = dout + (dir ? 0 : OUTHALF);

  // bf16 LDS. kb/qb rows padded to 24 shorts (48B): b128 frag reads land 2-way (free).
  __shared__ unsigned short kb[256 * 24];
  __shared__ unsigned short vb[256 * 16];
  __shared__ unsigned short qb[64 * 24];
  __shared__ unsigned short pb[4][16 * 40];  // per-wave P scratch, row stride 40 (2-way)
  __shared__ int widx[8];

  const int t = threadIdx.x;
  if (t < 8) widx[t] = (t < 4) ? idxK[((size_t)n * P2 + p) * 4 + t]
                               : idxV[((size_t)n * P2 + p) * 4 + (t - 4)];
  __syncthreads();

  // gather K,V: thread t handles key t (16 ch each), fp32 -> bf16
  {
    int kk = t >> 6, pix = t & 63;
    const float* sK = qkvQ + ((size_t)(n * P2 + widx[kk]) * 64 + pix) * COUT + 128 + h * 16;
    const float* sV = qkvV + ((size_t)(n * P2 + widx[4 + kk]) * 64 + pix) * COUT + 256 + h * 16;
    float4 a0 = *(const float4*)(sK + 0),  a1 = *(const float4*)(sK + 4);
    float4 a2 = *(const float4*)(sK + 8),  a3 = *(const float4*)(sK + 12);
    u16x8 k0, k1;
    k0[0]=f2bf(a0.x); k0[1]=f2bf(a0.y); k0[2]=f2bf(a0.z); k0[3]=f2bf(a0.w);
    k0[4]=f2bf(a1.x); k0[5]=f2bf(a1.y); k0[6]=f2bf(a1.z); k0[7]=f2bf(a1.w);
    k1[0]=f2bf(a2.x); k1[1]=f2bf(a2.y); k1[2]=f2bf(a2.z); k1[3]=f2bf(a2.w);
    k1[4]=f2bf(a3.x); k1[5]=f2bf(a3.y); k1[6]=f2bf(a3.z); k1[7]=f2bf(a3.w);
    *(u16x8*)&kb[t * 24] = k0;
    *(u16x8*)&kb[t * 24 + 8] = k1;
    float4 b0 = *(const float4*)(sV + 0),  b1 = *(const float4*)(sV + 4);
    float4 b2 = *(const float4*)(sV + 8),  b3 = *(const float4*)(sV + 12);
    u16x8 v0, v1;
    v0[0]=f2bf(b0.x); v0[1]=f2bf(b0.y); v0[2]=f2bf(b0.z); v0[3]=f2bf(b0.w);
    v0[4]=f2bf(b1.x); v0[5]=f2bf(b1.y); v0[6]=f2bf(b1.z); v0[7]=f2bf(b1.w);
    v1[0]=f2bf(b2.x); v1[1]=f2bf(b2.y); v1[2]=f2bf(b2.z); v1[3]=f2bf(b2.w);
    v1[4]=f2bf(b3.x); v1[5]=f2bf(b3.y); v1[6]=f2bf(b3.z); v1[7]=f2bf(b3.w);
    *(u16x8*)&vb[t * 16] = v0;
    *(u16x8*)&vb[t * 16 + 8] = v1;
  }
  // gather Q (pre-scaled)
  if (t < 64) {
    const float* sQ = qkvQ + ((size_t)(n * P2 + p) * 64 + t) * COUT + h * 16;
    float4 a0 = *(const float4*)(sQ + 0),  a1 = *(const float4*)(sQ + 4);
    float4 a2 = *(const float4*)(sQ + 8),  a3 = *(const float4*)(sQ + 12);
    u16x8 q0, q1;
    q0[0]=f2bf(a0.x*SCALE); q0[1]=f2bf(a0.y*SCALE); q0[2]=f2bf(a0.z*SCALE); q0[3]=f2bf(a0.w*SCALE);
    q0[4]=f2bf(a1.x*SCALE); q0[5]=f2bf(a1.y*SCALE); q0[6]=f2bf(a1.z*SCALE); q0[7]=f2bf(a1.w*SCALE);
    q1[0]=f2bf(a2.x*SCALE); q1[1]=f2bf(a2.y*SCALE); q1[2]=f2bf(a2.z*SCALE); q1[3]=f2bf(a2.w*SCALE);
    q1[4]=f2bf(a3.x*SCALE); q1[5]=f2bf(a3.y*SCALE); q1[6]=f2bf(a3.z*SCALE); q1[7]=f2bf(a3.w*SCALE);
    *(u16x8*)&qb[t * 24] = q0;
    *(u16x8*)&qb[t * 24 + 8] = q1;
  }
  __syncthreads();

  const int w = t >> 6;          // wave = row-tile
  const int lane = t & 63;
  const int qd = lane >> 4;      // quad
  const int m16 = lane & 15;

  // Q A-frag: A[m=lane&15][k=qd*8+j]; k>=16 is zero padding
  bf16x8 qf = (bf16x8)(short)0;
  if (qd < 2) qf = *(const bf16x8*)&qb[(w * 16 + m16) * 24 + qd * 8];

  f32x4 oacc = {0.f, 0.f, 0.f, 0.f};
  float mrun[4] = {-1e30f, -1e30f, -1e30f, -1e30f};
  float lrun[4] = {0.f, 0.f, 0.f, 0.f};
  const f32x4 zf = {0.f, 0.f, 0.f, 0.f};
  unsigned short* pbw = pb[w];

  for (int c = 0; c < 8; ++c) {   // 8 chunks of 32 keys
    // K B-frags: B[k=qd*8+j][n=m16], key = c*32 + ct*16 + m16
    bf16x8 kf0 = (bf16x8)(short)0, kf1 = (bf16x8)(short)0;
    if (qd < 2) {
      kf0 = *(const bf16x8*)&kb[(c * 32 + m16) * 24 + qd * 8];
      kf1 = *(const bf16x8*)&kb[(c * 32 + 16 + m16) * 24 + qd * 8];
    }
    f32x4 s0 = __builtin_amdgcn_mfma_f32_16x16x32_bf16(qf, kf0, zf, 0, 0, 0);
    f32x4 s1 = __builtin_amdgcn_mfma_f32_16x16x32_bf16(qf, kf1, zf, 0, 0, 0);

    // online softmax; C layout: col=lane&15 (key), row=qd*4+reg
    float al[4];
#pragma unroll
    for (int r = 0; r < 4; ++r) {
      float mc = fmaxf(s0[r], s1[r]);
      mc = fmaxf(mc, __shfl_xor(mc, 1));
      mc = fmaxf(mc, __shfl_xor(mc, 2));
      mc = fmaxf(mc, __shfl_xor(mc, 4));
      mc = fmaxf(mc, __shfl_xor(mc, 8));
      float mn = fmaxf(mrun[r], mc);
      float a = __expf(mrun[r] - mn);
      mrun[r] = mn;
      float p0 = __expf(s0[r] - mn);
      float p1 = __expf(s1[r] - mn);
      float rs = p0 + p1;
      rs += __shfl_xor(rs, 1);
      rs += __shfl_xor(rs, 2);
      rs += __shfl_xor(rs, 4);
      rs += __shfl_xor(rs, 8);
      lrun[r] = lrun[r] * a + rs;
      al[r] = a;
      pbw[(qd * 4 + r) * 40 + m16] = f2bf(p0);
      pbw[(qd * 4 + r) * 40 + 16 + m16] = f2bf(p1);
    }
#pragma unroll
    for (int r = 0; r < 4; ++r) oacc[r] *= al[r];
    __syncthreads();  // pb write -> read visibility (uniform across block)

    // P A-frag (full K=32) + V B-frag
    bf16x8 pf = *(const bf16x8*)&pbw[m16 * 40 + qd * 8];
    u16x8 vfu;
#pragma unroll
    for (int j = 0; j < 8; ++j) vfu[j] = vb[(c * 32 + qd * 8 + j) * 16 + m16];
    oacc = __builtin_amdgcn_mfma_f32_16x16x32_bf16(pf, *(bf16x8*)&vfu, oacc, 0, 0, 0);
    __syncthreads();  // protect pb before next chunk's writes
  }

  const int wr = p / NWIN, wc = p % NWIN;
#pragma unroll
  for (int r = 0; r < 4; ++r) {
    float inv = 1.f / lrun[r];
    int pix = w * 16 + qd * 4 + r;
    int a = wr * 8 + (pix >> 3), b = wc * 8 + (pix & 7);
    outp[(((size_t)n * HWD + a) * HWD + b) * CIN + h * 16 + m16] = oacc[r] * inv;
  }
}

// ---------------- depthwise 3x3 LEPE + add into d_out ----------------
__global__ __launch_bounds__(128) void lepe_kernel(
    const float* __restrict__ qkvx, const float* __restrict__ qkvy,
    const float* __restrict__ wlx, const float* __restrict__ blx,
    const float* __restrict__ wly, const float* __restrict__ bly,
    float* __restrict__ dout)
{
  const int a = blockIdx.x, b = blockIdx.y;
  const int n = blockIdx.z >> 1, br = blockIdx.z & 1;
  const float* qkv = br ? qkvy : qkvx;
  const float* wl = br ? wly : wlx;
  const float* bl = br ? bly : blx;
  const size_t OUTHALF = (size_t)NB * HWD * HWD * CIN;
  float* outp = dout + (br ? OUTHALF : 0);
  const int c = threadIdx.x;

  float s = bl[c];
#pragma unroll
  for (int di = 0; di < 3; ++di) {
    int aa = a + di - 1;
    if ((unsigned)aa < (unsigned)HWD) {
#pragma unroll
      for (int dj = 0; dj < 3; ++dj) {
        int bb = b + dj - 1;
        if ((unsigned)bb < (unsigned)HWD) {
          int pp = (aa >> 3) * NWIN + (bb >> 3);
          int pix = ((aa & 7) << 3) + (bb & 7);
          float v = qkv[(((size_t)(n * P2 + pp)) * 64 + pix) * COUT + 256 + c];
          s = fmaf(v, wl[c * 9 + di * 3 + dj], s);
        }
      }
    }
  }
  size_t o = (((size_t)n * HWD + a) * HWD + b) * CIN + c;
  outp[o] += s;
}

extern "C" void kernel_launch(void* const* d_in, const int* in_sizes, int n_in,
                              void* d_out, int out_size, void* d_ws, size_t ws_size,
                              hipStream_t stream) {
  const float* x        = (const float*)d_in[0];
  const float* y        = (const float*)d_in[1];
  const float* w_qkv_x  = (const float*)d_in[2];
  const float* b_qkv_x  = (const float*)d_in[3];
  const float* w_qkv_y  = (const float*)d_in[4];
  const float* b_qkv_y  = (const float*)d_in[5];
  const float* w_lepe_x = (const float*)d_in[6];
  const float* b_lepe_x = (const float*)d_in[7];
  const float* w_lepe_y = (const float*)d_in[8];
  const float* b_lepe_y = (const float*)d_in[9];
  float* out = (float*)d_out;
  float* ws  = (float*)d_ws;

  const size_t qkv_sz = (size_t)NB * P2 * 64 * COUT;
  const size_t win_sz = (size_t)NB * P2 * 128;
  float* qkvx = ws;
  float* qkvy = qkvx + qkv_sz;
  float* qwx  = qkvy + qkv_sz;
  float* kwx  = qwx + win_sz;
  float* qwy  = kwx + win_sz;
  float* kwy  = qwy + win_sz;
  int*   idxx = (int*)(kwy + win_sz);
  int*   idxy = idxx + NB * P2 * 4;

  qkv_proj_kernel<<<dim3(P2, NB, 2), 384, 0, stream>>>(
      x, y, w_qkv_x, b_qkv_x, w_qkv_y, b_qkv_y, qkvx, qkvy, qwx, kwx, qwy, kwy);
  route_kernel<<<dim3(2, NB), 256, 0, stream>>>(qwx, kwx, qwy, kwy, idxx, idxy);
  attn_kernel<<<dim3(P2, NB, 16), 256, 0, stream>>>(qkvx, qkvy, idxx, idxy, out);
  lepe_kernel<<<dim3(HWD, HWD, 2 * NB), 128, 0, stream>>>(
      qkvx, qkvy, w_lepe_x, b_lepe_x, w_lepe_y, b_lepe_y, out);
}

// Round 3
// 237.535 us; speedup vs baseline: 1.8470x; 1.7788x over previous
//
#include <hip/hip_runtime.h>

#define HWD 56
#define NWIN 7
#define P2 49
#define CIN 128
#define COUT 384
#define NB 8
#define SCALE 0.08838834764831843f

typedef __attribute__((ext_vector_type(8))) short bf16x8;
typedef __attribute__((ext_vector_type(4))) float f32x4;
typedef __attribute__((ext_vector_type(8))) unsigned short u16x8;
typedef unsigned short ushort_t;

__device__ inline unsigned short f2bf(float f) {
  unsigned int u = __float_as_uint(f);
  unsigned int r = (u + 0x7fffu + ((u >> 16) & 1u)) >> 16;
  return (unsigned short)r;
}
__device__ inline float bf2f(unsigned short b) {
  return __uint_as_float(((unsigned int)b) << 16);
}

// bumped row index for 16-ch LDS tiles: stride 24 shorts + 16B bump every 8 rows
// keeps 16B alignment and spreads banks for both staging writes and frag reads
#define KIDX(k) ((k) * 24 + (((k) >> 3) << 3))

// ---------------- window mean of x + projection -> q_win, k_win (all fp32) ----------------
// grid (49, 8, 2), block 256
__global__ __launch_bounds__(256) void meanproj_kernel(
    const float* __restrict__ xin, const float* __restrict__ yin,
    const float* __restrict__ Wx, const float* __restrict__ Bx,
    const float* __restrict__ Wy, const float* __restrict__ By,
    float* __restrict__ qwx, float* __restrict__ kwx,
    float* __restrict__ qwy, float* __restrict__ kwy)
{
  const int p = blockIdx.x, n = blockIdx.y, br = blockIdx.z;
  const float* X  = br ? yin : xin;
  const float* W  = br ? Wy  : Wx;
  const float* Bv = br ? By  : Bx;
  float* qw = br ? qwy : qwx;
  float* kw = br ? kwy : kwx;

  __shared__ float sm[2][128];
  __shared__ float mxs[128];
  const int t = threadIdx.x;
  const int wr = p / NWIN, wc = p % NWIN;
  const int ch = t & 127, half = t >> 7;

  float s = 0.f;
#pragma unroll 4
  for (int i = 0; i < 32; ++i) {
    int pix = half * 32 + i;
    int a = wr * 8 + (pix >> 3), b = wc * 8 + (pix & 7);
    s += X[(((size_t)n * HWD + a) * HWD + b) * CIN + ch];
  }
  sm[half][ch] = s;
  __syncthreads();
  if (t < 128) mxs[t] = (sm[0][t] + sm[1][t]) * (1.f / 64.f);
  __syncthreads();

  // project: cout = t (0..255); q_win/k_win = mean @ W + b  (fp32 exact path for routing)
  float acc = Bv[t];
#pragma unroll 8
  for (int k = 0; k < 128; ++k) acc = fmaf(mxs[k], W[(size_t)k * COUT + t], acc);
  if (t < 128) qw[(n * P2 + p) * 128 + t] = acc;
  else         kw[(n * P2 + p) * 128 + (t - 128)] = acc;
}

// ---------------- routing: top-4 window indices (fp32) ----------------
// grid (2, 8), block 256
__global__ __launch_bounds__(256) void route_kernel(
    const float* __restrict__ qwx, const float* __restrict__ kwx,
    const float* __restrict__ qwy, const float* __restrict__ kwy,
    int* __restrict__ idxx, int* __restrict__ idxy)
{
  const int br = blockIdx.x, n = blockIdx.y;
  const float* qw = br ? qwy : qwx;
  const float* kw = br ? kwy : kwx;
  int* idx = br ? idxy : idxx;

  __shared__ float qs[P2][128];
  __shared__ float ks[P2][128];
  __shared__ float ls[P2][52];
  const int t = threadIdx.x;
  for (int e = t; e < P2 * 128; e += 256) {
    qs[e >> 7][e & 127] = qw[(size_t)n * P2 * 128 + e];
    ks[e >> 7][e & 127] = kw[(size_t)n * P2 * 128 + e];
  }
  __syncthreads();
  for (int pair = t; pair < P2 * P2; pair += 256) {
    int r = pair / P2, j = pair % P2;
    float d = 0.f;
#pragma unroll
    for (int c4 = 0; c4 < 32; ++c4) {
      float4 a = *(const float4*)&qs[r][c4 * 4];
      float4 b = *(const float4*)&ks[j][c4 * 4];
      d = fmaf(a.x, b.x, d); d = fmaf(a.y, b.y, d);
      d = fmaf(a.z, b.z, d); d = fmaf(a.w, b.w, d);
    }
    ls[r][j] = d;  // positive scale is monotone: ordering identical
  }
  __syncthreads();
  if (t < P2) {
    int ch[4];
    for (int s = 0; s < 4; ++s) {
      float best = -1e30f; int bi = 0;
      for (int j = 0; j < P2; ++j) {
        bool taken = false;
        for (int u = 0; u < s; ++u) taken = taken || (ch[u] == j);
        if (!taken && ls[t][j] > best) { best = ls[t][j]; bi = j; }
      }
      ch[s] = bi;
      idx[((size_t)n * P2 + t) * 4 + s] = bi;
    }
  }
}

// ---------------- qkv = x @ W + b, bf16 MFMA, output [gw][ch 384][pix 64] bf16 ----------------
// grid (196, 3, 2): m-tile(128 tok = 2 windows), n-tile(128 couts), branch. block 256 = 4 waves.
#define AS 136
__global__ __launch_bounds__(256) void qkv_gemm_kernel(
    const float* __restrict__ xin, const float* __restrict__ yin,
    const float* __restrict__ Wx, const float* __restrict__ Bx,
    const float* __restrict__ Wy, const float* __restrict__ By,
    ushort_t* __restrict__ qkvx, ushort_t* __restrict__ qkvy)
{
  const int mt = blockIdx.x, nt = blockIdx.y, br = blockIdx.z;
  const float* X  = br ? yin : xin;
  const float* W  = br ? Wy  : Wx;
  const float* Bv = br ? By  : Bx;
  ushort_t* out = br ? qkvy : qkvx;

  __shared__ ushort_t a_s[128 * AS];  // [token][k]
  __shared__ ushort_t b_s[128 * AS];  // [cout][k] (transposed)

  const int t = threadIdx.x;

  // stage A: 128 tokens x 128 k, fp32->bf16
#pragma unroll
  for (int it = 0; it < 16; ++it) {
    int tok = it * 8 + (t >> 5);
    int ch4 = (t & 31) * 4;
    int gw = mt * 2 + (tok >> 6);
    int n = gw / P2, p = gw % P2;
    int pix = tok & 63;
    int a = (p / NWIN) * 8 + (pix >> 3), b = (p % NWIN) * 8 + (pix & 7);
    float4 v = *(const float4*)&X[(((size_t)n * HWD + a) * HWD + b) * CIN + ch4];
    ushort4 o = {f2bf(v.x), f2bf(v.y), f2bf(v.z), f2bf(v.w)};
    *(ushort4*)&a_s[tok * AS + ch4] = o;
  }
  // stage B: W[k][nt*128 + c] -> b_s[c][k]
#pragma unroll
  for (int it = 0; it < 16; ++it) {
    int k = it * 8 + (t >> 5);
    int c4 = (t & 31) * 4;
    float4 v = *(const float4*)&W[(size_t)k * COUT + nt * 128 + c4];
    b_s[(c4 + 0) * AS + k] = f2bf(v.x);
    b_s[(c4 + 1) * AS + k] = f2bf(v.y);
    b_s[(c4 + 2) * AS + k] = f2bf(v.z);
    b_s[(c4 + 3) * AS + k] = f2bf(v.w);
  }
  __syncthreads();

  const int wv = t >> 6, wm = wv >> 1, wn = wv & 1;
  const int lane = t & 63, qd = lane >> 4, m16 = lane & 15;

  f32x4 acc[4][4];
#pragma unroll
  for (int i = 0; i < 4; ++i)
#pragma unroll
    for (int j = 0; j < 4; ++j) acc[i][j] = (f32x4){0.f, 0.f, 0.f, 0.f};

#pragma unroll
  for (int ks = 0; ks < 4; ++ks) {
    bf16x8 af[4], bfr[4];
#pragma unroll
    for (int fi = 0; fi < 4; ++fi)
      af[fi] = *(const bf16x8*)&a_s[(wm * 64 + fi * 16 + m16) * AS + ks * 32 + qd * 8];
#pragma unroll
    for (int fj = 0; fj < 4; ++fj)
      bfr[fj] = *(const bf16x8*)&b_s[(wn * 64 + fj * 16 + m16) * AS + ks * 32 + qd * 8];
#pragma unroll
    for (int fi = 0; fi < 4; ++fi)
#pragma unroll
      for (int fj = 0; fj < 4; ++fj)
        acc[fi][fj] = __builtin_amdgcn_mfma_f32_16x16x32_bf16(af[fi], bfr[fj], acc[fi][fj], 0, 0, 0);
  }

  // epilogue: +bias, bf16, store transposed [gw][ch][pix]
  const int gw = mt * 2 + wm;
#pragma unroll
  for (int fj = 0; fj < 4; ++fj) {
    int chb = nt * 128 + wn * 64 + fj * 16 + m16;
    float bias = Bv[chb];
#pragma unroll
    for (int fi = 0; fi < 4; ++fi) {
      int pixb = fi * 16 + qd * 4;
      ushort4 st = {f2bf(acc[fi][fj][0] + bias), f2bf(acc[fi][fj][1] + bias),
                    f2bf(acc[fi][fj][2] + bias), f2bf(acc[fi][fj][3] + bias)};
      *(ushort4*)&out[((size_t)gw * COUT + chb) * 64 + pixb] = st;
    }
  }
}

// ---------------- fused gather + MFMA attention + LEPE (cross branches) ----------------
// grid (49, 8, 16): z = head*2 + dir; block 256 = 4 waves, wave w owns q-rows [16w,16w+16)
// S^T = K*Q^T, O^T = V^T*P^T: softmax state lane-local per query row, no barriers in K-loop.
__global__ __launch_bounds__(256) void attn_kernel(
    const ushort_t* __restrict__ qkvx, const ushort_t* __restrict__ qkvy,
    const int* __restrict__ idxx, const int* __restrict__ idxy,
    const float* __restrict__ wlx, const float* __restrict__ blx,
    const float* __restrict__ wly, const float* __restrict__ bly,
    float* __restrict__ dout)
{
  const int p = blockIdx.x, n = blockIdx.y, z = blockIdx.z;
  const int h = z >> 1, dir = z & 1;
  const ushort_t* qkvQ = dir ? qkvy : qkvx;
  const ushort_t* qkvV = dir ? qkvx : qkvy;
  const int* idxK = dir ? idxy : idxx;
  const int* idxV = dir ? idxx : idxy;
  const float* wl = dir ? wlx : wly;   // dir0 writes out_y -> lepe_y
  const float* bl = dir ? blx : bly;
  const size_t OUTHALF = (size_t)NB * HWD * HWD * CIN;
  float* outp = dout + (dir ? 0 : OUTHALF);

  __shared__ ushort_t kb[6400];        // [key 256][ch 16] bumped rows
  __shared__ ushort_t vt[16 * 264];    // [ch 16][key 256+pad] (V transposed = direct copy)
  __shared__ ushort_t qb[1600];        // [row 64][ch 16] bumped rows
  __shared__ int widx[8];

  const int t = threadIdx.x;
  if (t < 8) widx[t] = (t < 4) ? idxK[((size_t)n * P2 + p) * 4 + t]
                               : idxV[((size_t)n * P2 + p) * 4 + (t - 4)];
  __syncthreads();

  const int wv = t >> 6, r = t & 63;

  // K: wave wv stages window widx[wv]; global layout [gw][ch][pix] -> kb[key][ch] packed b32
  {
    int ch2 = r >> 3, g = r & 7, pixg = g * 8;
    const ushort_t* src = qkvQ + ((size_t)(n * P2 + widx[wv]) * COUT + 128 + h * 16 + 2 * ch2) * 64 + pixg;
    u16x8 v0 = *(const u16x8*)src;
    u16x8 v1 = *(const u16x8*)(src + 64);
#pragma unroll
    for (int i = 0; i < 8; ++i) {
      int key = wv * 64 + pixg + i;
      *(unsigned int*)&kb[KIDX(key) + 2 * ch2] = (unsigned int)v0[i] | ((unsigned int)v1[i] << 16);
    }
  }
  // V: wave wv stages window widx[4+wv] transposed-direct into vt[ch][key]
  {
    int ch_l = r >> 2, pixg = (r & 3) * 16;
    const ushort_t* src = qkvV + ((size_t)(n * P2 + widx[4 + wv]) * COUT + 256 + h * 16 + ch_l) * 64 + pixg;
    *(u16x8*)&vt[ch_l * 264 + wv * 64 + pixg] = *(const u16x8*)src;
    *(u16x8*)&vt[ch_l * 264 + wv * 64 + pixg + 8] = *(const u16x8*)(src + 8);
  }
  // Q: window p -> qb[row][ch] packed b32
  if (t < 64) {
    int ch2 = t >> 3, g = t & 7, pixg = g * 8;
    const ushort_t* src = qkvQ + ((size_t)(n * P2 + p) * COUT + h * 16 + 2 * ch2) * 64 + pixg;
    u16x8 v0 = *(const u16x8*)src;
    u16x8 v1 = *(const u16x8*)(src + 64);
#pragma unroll
    for (int i = 0; i < 8; ++i)
      *(unsigned int*)&qb[KIDX(pixg + i) + 2 * ch2] = (unsigned int)v0[i] | ((unsigned int)v1[i] << 16);
  }
  __syncthreads();

  const int qd = (t & 63) >> 4, m16 = t & 15;

  bf16x8 qf = (bf16x8)(short)0;
  if (qd < 2) qf = *(const bf16x8*)&qb[KIDX(wv * 16 + m16) + qd * 8];

  f32x4 oacc = {0.f, 0.f, 0.f, 0.f};
  float mrun = -1e30f, lrun = 0.f;
  const f32x4 zf = {0.f, 0.f, 0.f, 0.f};

  for (int c = 0; c < 8; ++c) {
    bf16x8 kf0 = (bf16x8)(short)0, kf1 = (bf16x8)(short)0;
    if (qd < 2) {
      kf0 = *(const bf16x8*)&kb[KIDX(c * 32 + m16) + qd * 8];
      kf1 = *(const bf16x8*)&kb[KIDX(c * 32 + 16 + m16) + qd * 8];
    }
    // S^T: lane holds keys c*32+qd*4+r (s0), +16 (s1) for query row m16
    f32x4 s0 = __builtin_amdgcn_mfma_f32_16x16x32_bf16(kf0, qf, zf, 0, 0, 0);
    f32x4 s1 = __builtin_amdgcn_mfma_f32_16x16x32_bf16(kf1, qf, zf, 0, 0, 0);

    float mc = -1e30f;
#pragma unroll
    for (int rr = 0; rr < 4; ++rr) {
      s0[rr] *= SCALE; s1[rr] *= SCALE;
      mc = fmaxf(mc, fmaxf(s0[rr], s1[rr]));
    }
    mc = fmaxf(mc, __shfl_xor(mc, 16));
    mc = fmaxf(mc, __shfl_xor(mc, 32));
    float mn = fmaxf(mrun, mc);
    float alpha = __expf(mrun - mn);
    mrun = mn;
    float p0[4], p1[4], rs = 0.f;
#pragma unroll
    for (int rr = 0; rr < 4; ++rr) {
      p0[rr] = __expf(s0[rr] - mn);
      p1[rr] = __expf(s1[rr] - mn);
      rs += p0[rr] + p1[rr];
    }
    rs += __shfl_xor(rs, 16);
    rs += __shfl_xor(rs, 32);
    lrun = lrun * alpha + rs;
#pragma unroll
    for (int rr = 0; rr < 4; ++rr) oacc[rr] *= alpha;

    // pack p0|p1 as bf16 pair, shuffle into P^T B-frag: B[k=qd*8+j][n=m16]
    int pk[4];
#pragma unroll
    for (int rr = 0; rr < 4; ++rr)
      pk[rr] = (int)((unsigned int)f2bf(p0[rr]) | ((unsigned int)f2bf(p1[rr]) << 16));
    u16x8 pfu;
#pragma unroll
    for (int j = 0; j < 8; ++j) {
      int srcl = (((qd & 1) * 2 + (j >> 2)) << 4) + m16;
      int w = __shfl(pk[j & 3], srcl);
      pfu[j] = (qd < 2) ? (unsigned short)(w & 0xffff) : (unsigned short)((unsigned)w >> 16);
    }
    bf16x8 vtf = *(const bf16x8*)&vt[m16 * 264 + c * 32 + qd * 8];
    oacc = __builtin_amdgcn_mfma_f32_16x16x32_bf16(vtf, *(bf16x8*)&pfu, oacc, 0, 0, 0);
  }

  // epilogue: lane holds O^T[ch = h*16+qd*4+r][qrow = wv*16+m16]; softmax state lane-local
  const float inv = 1.f / lrun;
  const int wr = p / NWIN, wc = p % NWIN;
  const int pix = wv * 16 + m16;
  const int ga = wr * 8 + (pix >> 3), gb = wc * 8 + (pix & 7);
  const int ch0 = h * 16 + qd * 4;

  // LEPE (depthwise 3x3 over v of this branch's V tensor) fused
  float wlv[4][9], lep[4];
#pragma unroll
  for (int rr = 0; rr < 4; ++rr) {
    lep[rr] = bl[ch0 + rr];
#pragma unroll
    for (int tap = 0; tap < 9; ++tap) wlv[rr][tap] = wl[(ch0 + rr) * 9 + tap];
  }
#pragma unroll
  for (int di = 0; di < 3; ++di) {
    int aa = ga + di - 1;
    if ((unsigned)aa < (unsigned)HWD) {
#pragma unroll
      for (int dj = 0; dj < 3; ++dj) {
        int bb = gb + dj - 1;
        if ((unsigned)bb < (unsigned)HWD) {
          int pp = (aa >> 3) * NWIN + (bb >> 3);
          int pix2 = ((aa & 7) << 3) + (bb & 7);
          const ushort_t* vsrc = qkvV + ((size_t)(n * P2 + pp) * COUT + 256 + ch0) * 64 + pix2;
#pragma unroll
          for (int rr = 0; rr < 4; ++rr)
            lep[rr] = fmaf(bf2f(vsrc[rr * 64]), wlv[rr][di * 3 + dj], lep[rr]);
        }
      }
    }
  }

  float4 o = {oacc[0] * inv + lep[0], oacc[1] * inv + lep[1],
              oacc[2] * inv + lep[2], oacc[3] * inv + lep[3]};
  *(float4*)&outp[(((size_t)n * HWD + ga) * HWD + gb) * CIN + ch0] = o;
}

extern "C" void kernel_launch(void* const* d_in, const int* in_sizes, int n_in,
                              void* d_out, int out_size, void* d_ws, size_t ws_size,
                              hipStream_t stream) {
  const float* x        = (const float*)d_in[0];
  const float* y        = (const float*)d_in[1];
  const float* w_qkv_x  = (const float*)d_in[2];
  const float* b_qkv_x  = (const float*)d_in[3];
  const float* w_qkv_y  = (const float*)d_in[4];
  const float* b_qkv_y  = (const float*)d_in[5];
  const float* w_lepe_x = (const float*)d_in[6];
  const float* b_lepe_x = (const float*)d_in[7];
  const float* w_lepe_y = (const float*)d_in[8];
  const float* b_lepe_y = (const float*)d_in[9];
  float* out = (float*)d_out;

  const size_t qkv_sz = (size_t)NB * P2 * 64 * COUT;   // bf16 elements
  const size_t win_sz = (size_t)NB * P2 * 128;         // fp32
  ushort_t* qkvx = (ushort_t*)d_ws;
  ushort_t* qkvy = qkvx + qkv_sz;
  float* qwx = (float*)(qkvy + qkv_sz);
  float* kwx = qwx + win_sz;
  float* qwy = kwx + win_sz;
  float* kwy = qwy + win_sz;
  int* idxx = (int*)(kwy + win_sz);
  int* idxy = idxx + NB * P2 * 4;

  meanproj_kernel<<<dim3(P2, NB, 2), 256, 0, stream>>>(
      x, y, w_qkv_x, b_qkv_x, w_qkv_y, b_qkv_y, qwx, kwx, qwy, kwy);
  route_kernel<<<dim3(2, NB), 256, 0, stream>>>(qwx, kwx, qwy, kwy, idxx, idxy);
  qkv_gemm_kernel<<<dim3(196, 3, 2), 256, 0, stream>>>(
      x, y, w_qkv_x, b_qkv_x, w_qkv_y, b_qkv_y, qkvx, qkvy);
  attn_kernel<<<dim3(P2, NB, 16), 256, 0, stream>>>(
      qkvx, qkvy, idxx, idxy, w_lepe_x, b_lepe_x, w_lepe_y, b_lepe_y, out);
}